// Round 2
// baseline (689.972 us; speedup 1.0000x reference)
//
#include <hip/hip_runtime.h>
#include <math.h>

// ---------------------------------------------------------------------------
// TransferSH with index-locality binning.
//
// The 360MB higher_sh array is randomly gathered (180B rows, 4B-aligned) ->
// ~304B of HBM lines fetched per point with no reuse (~610MB). A 256-bin
// counting sort of the point order makes each ~1.4MB bin segment L2/L3
// resident while consumed, dropping higher_sh HBM fetch to its distinct-line
// footprint (~295MB). positions/out become 24MB L3-resident gather/scatter.
//
// Pipeline (all on one stream): zero -> histogram -> scan -> scatter-perm ->
// main (perm-ordered). Falls back to the direct fused kernel if ws is too
// small for the permutation array.
// ---------------------------------------------------------------------------

#define NB 256  // bins

// ---- tiny zero: hist[256] + cursors[256] ----------------------------------
__global__ __launch_bounds__(512) void zero_kernel(unsigned* __restrict__ p)
{
    p[threadIdx.x] = 0u;
}

// ---- histogram of bin(idx) -------------------------------------------------
__global__ __launch_bounds__(256) void hist_kernel(
    const int* __restrict__ idx, unsigned* __restrict__ hist,
    float scale, int n)
{
    __shared__ unsigned lh[NB];
    const int t = threadIdx.x;
    lh[t] = 0u;
    __syncthreads();
    for (long e = (long)blockIdx.x * 256 + t; e < n; e += (long)gridDim.x * 256) {
        unsigned b = (unsigned)(idx[e] * scale);
        if (b > NB - 1u) b = NB - 1u;
        atomicAdd(&lh[b], 1u);
    }
    __syncthreads();
    unsigned c = lh[t];
    if (c) atomicAdd(&hist[t], c);
}

// ---- exclusive scan of 256 bins (1 wave, 4 bins/lane) ----------------------
__global__ __launch_bounds__(64) void scan_kernel(
    const unsigned* __restrict__ hist, unsigned* __restrict__ cursors)
{
    const int t = threadIdx.x;
    unsigned v0 = hist[4 * t + 0], v1 = hist[4 * t + 1];
    unsigned v2 = hist[4 * t + 2], v3 = hist[4 * t + 3];
    unsigned s4 = v0 + v1 + v2 + v3;
    unsigned s = s4;
    #pragma unroll
    for (int off = 1; off < 64; off <<= 1) {
        unsigned x = __shfl_up(s, off);
        if (t >= off) s += x;
    }
    unsigned base = s - s4;  // exclusive prefix
    cursors[4 * t + 0] = base; base += v0;
    cursors[4 * t + 1] = base; base += v1;
    cursors[4 * t + 2] = base; base += v2;
    cursors[4 * t + 3] = base;
}

// ---- scatter permutation: block-aggregated bin reservation -----------------
#define SC_ELEMS 16   // elements per thread -> 4096 per block
__global__ __launch_bounds__(256) void scatter_kernel(
    const int* __restrict__ idx, unsigned* __restrict__ cursors,
    int* __restrict__ perm, float scale, int n)
{
    __shared__ unsigned lhist[NB];
    __shared__ unsigned lbase[NB];
    const int t = threadIdx.x;
    const long base0 = (long)blockIdx.x * (256L * SC_ELEMS);

    lhist[t] = 0u;
    __syncthreads();

    unsigned mybin[SC_ELEMS];
    #pragma unroll
    for (int k = 0; k < SC_ELEMS; ++k) {
        long e = base0 + (long)k * 256 + t;
        unsigned b = 0xFFFFFFFFu;
        if (e < n) {
            b = (unsigned)(idx[e] * scale);
            if (b > NB - 1u) b = NB - 1u;
            atomicAdd(&lhist[b], 1u);
        }
        mybin[k] = b;
    }
    __syncthreads();
    unsigned c = lhist[t];
    if (c) lbase[t] = atomicAdd(&cursors[t], c);
    lhist[t] = 0u;   // reuse as local rank cursor
    __syncthreads();
    #pragma unroll
    for (int k = 0; k < SC_ELEMS; ++k) {
        unsigned b = mybin[k];
        if (b != 0xFFFFFFFFu) {
            unsigned r = atomicAdd(&lhist[b], 1u);
            perm[lbase[b] + r] = (int)(base0 + (long)k * 256 + t);
        }
    }
}

// ---- main kernel, perm-ordered --------------------------------------------
__global__ __launch_bounds__(256) void transfer_sh_perm(
    const float* __restrict__ positions,
    const int*   __restrict__ indexes,
    const int*   __restrict__ perm,
    const float* __restrict__ cam_pos,
    const float* __restrict__ glo,
    const float* __restrict__ base_sh,
    const float* __restrict__ higher_sh,
    const float* __restrict__ w1,
    const float* __restrict__ b1,
    const float* __restrict__ ln_w,
    const float* __restrict__ ln_b,
    const float* __restrict__ w2,
    const float* __restrict__ b2,
    float* __restrict__ out,            // (N,3)
    float* __restrict__ mean_out,       // scalar tail of out buffer
    int n)
{
    __shared__ float aff[12];
    __shared__ float hsh[32];
    __shared__ float ssh[12];

    const int t = threadIdx.x;

    // XCD-aware bijective swizzle: give each XCD a contiguous chunk of the
    // (bin-sorted) point order so a bin's segment lives in ONE XCD's L2.
    const unsigned nwg = gridDim.x;
    const unsigned q = nwg >> 3, r = nwg & 7u;
    const unsigned xcd = blockIdx.x & 7u, pos = blockIdx.x >> 3;
    const unsigned wg = (xcd < r ? xcd * (q + 1u)
                                 : r * (q + 1u) + (xcd - r) * q) + pos;

    const int j = (int)wg * 256 + t;
    const bool active = (j < n);
    const int je = active ? j : (n - 1);   // barrier-safe tail clamp
    const int i = perm[je];                // original point id

    // ---- issue ALL per-point loads first: gather latency overlaps the
    //      per-block MLP prologue below ----
    unsigned idx = (unsigned)indexes[i];

    float px = positions[3 * i + 0];
    float py = positions[3 * i + 1];
    float pz = positions[3 * i + 2];

    float a0 = base_sh[3 * idx + 0];
    float a1 = base_sh[3 * idx + 1];
    float a2 = base_sh[3 * idx + 2];

    // higher_sh: 45 floats at float-offset fo = 45*idx (4B-aligned only).
    // Read the enclosing 16B-aligned 192B window as 12 float4 (misalign
    // m = fo&3 <= 3, m+45 <= 48 always covers the row; window touches
    // exactly the same HBM lines as the row itself).
    unsigned fo = 45u * idx;
    const float4* W = (const float4*)(higher_sh + (fo & ~3u));
    float4 v[12];
    #pragma unroll
    for (int qq = 0; qq < 12; ++qq) v[qq] = W[qq];

    // ---- per-block affine MLP (redundant per block; weights L2-resident) ----
    if (t < 64) {
        float h = 0.f;
        if (t < 32) {
            h = b1[t];
            #pragma unroll
            for (int k = 0; k < 16; ++k) h += glo[k] * w1[k * 32 + t];
        }
        float s = h;
        #pragma unroll
        for (int off = 32; off > 0; off >>= 1) s += __shfl_down(s, off);
        float mu = __shfl(s, 0) * (1.f / 32.f);
        float d = (t < 32) ? (h - mu) : 0.f;
        float v2 = d * d;
        #pragma unroll
        for (int off = 32; off > 0; off >>= 1) v2 += __shfl_down(v2, off);
        float var = __shfl(v2, 0) * (1.f / 32.f);
        float inv = rsqrtf(var + 1e-5f);
        if (t < 32) {
            float hv = (h - mu) * inv * ln_w[t] + ln_b[t];
            hsh[t] = hv > 0.f ? hv : 0.f;
        }
    }
    __syncthreads();
    if (t < 12) {
        float s2 = b2[t];
        #pragma unroll
        for (int jj = 0; jj < 32; ++jj) s2 += hsh[jj] * w2[jj * 12 + t];
        s2 *= 1e-12f;                                 // affine_res element
        ssh[t] = fabsf(s2);
        float e = ((t & 3) == (t >> 2)) ? 1.f : 0.f;  // eye(3,4) diag
        aff[t] = s2 + e;
    }
    __syncthreads();
    if (blockIdx.x == 0 && t == 0) {
        float sa = 0.f;
        #pragma unroll
        for (int q2 = 0; q2 < 12; ++q2) sa += ssh[q2];
        *mean_out = sa * (1.f / 12.f);
    }

    // ---- per-point compute ----
    float dx = px - cam_pos[0];
    float dy = py - cam_pos[1];
    float dz = pz - cam_pos[2];
    float rn = rsqrtf(dx * dx + dy * dy + dz * dz);
    float x = dx * rn, y = dy * rn, z = dz * rn;

    float xx = x * x, yy = y * y, zz = z * z;
    float xy = x * y, yz = y * z, xz = x * z;

    float b[16];
    b[1]  = -0.4886025119029199f * y;
    b[2]  =  0.4886025119029199f * z;
    b[3]  = -0.4886025119029199f * x;
    b[4]  =  1.0925484305920792f * xy;
    b[5]  = -1.0925484305920792f * yz;
    b[6]  =  0.31539156525252005f * (2.f * zz - xx - yy);
    b[7]  = -1.0925484305920792f * xz;
    b[8]  =  0.5462742152960396f * (xx - yy);
    b[9]  = -0.5900435899266435f * y * (3.f * xx - yy);
    b[10] =  2.890611442640554f  * xy * z;
    b[11] = -0.4570457994644658f * y * (4.f * zz - xx - yy);
    b[12] =  0.3731763325901154f * z * (2.f * zz - 3.f * xx - 3.f * yy);
    b[13] = -0.4570457994644658f * x * (4.f * zz - xx - yy);
    b[14] =  1.445305721320277f  * z * (xx - yy);
    b[15] = -0.5900435899266435f * x * (xx - yy);

    const float C0 = 0.28209479177387814f;
    float c0 = a0 * C0 + 0.5f;
    float c1 = a1 * C0 + 0.5f;
    float c2 = a2 * C0 + 0.5f;

    float Wf[48];
    #pragma unroll
    for (int qq = 0; qq < 12; ++qq) {
        Wf[4 * qq + 0] = v[qq].x; Wf[4 * qq + 1] = v[qq].y;
        Wf[4 * qq + 2] = v[qq].z; Wf[4 * qq + 3] = v[qq].w;
    }

#define ACC(M)                                      \
    {                                               \
        _Pragma("unroll")                           \
        for (int k = 0; k < 15; ++k) {              \
            c0 += Wf[(M) + k]      * b[k + 1];      \
            c1 += Wf[(M) + 15 + k] * b[k + 1];      \
            c2 += Wf[(M) + 30 + k] * b[k + 1];      \
        }                                           \
    }
    switch (fo & 3u) {
        case 0: ACC(0) break;
        case 1: ACC(1) break;
        case 2: ACC(2) break;
        default: ACC(3) break;
    }
#undef ACC

    if (active) {
        #pragma unroll
        for (int rr = 0; rr < 3; ++rr) {
            float vv = c0 * aff[4 * rr + 0] + c1 * aff[4 * rr + 1] +
                       c2 * aff[4 * rr + 2] + aff[4 * rr + 3];
            vv = fminf(fmaxf(vv, 0.f), 1.f);
            out[3 * i + rr] = vv;   // scatter; L3-coalesced (24MB resident)
        }
    }
}

// ---- fallback: direct fused kernel (round-1 version) ----------------------
__global__ __launch_bounds__(256) void transfer_sh_fused(
    const float* __restrict__ positions,
    const int*   __restrict__ indexes,
    const float* __restrict__ cam_pos,
    const float* __restrict__ glo,
    const float* __restrict__ base_sh,
    const float* __restrict__ higher_sh,
    const float* __restrict__ w1,
    const float* __restrict__ b1,
    const float* __restrict__ ln_w,
    const float* __restrict__ ln_b,
    const float* __restrict__ w2,
    const float* __restrict__ b2,
    float* __restrict__ out,
    float* __restrict__ mean_out,
    int n)
{
    __shared__ float aff[12];
    __shared__ float hsh[32];
    __shared__ float ssh[12];

    const int t = threadIdx.x;
    const int i = blockIdx.x * 256 + t;
    const bool active = (i < n);
    const int ie = active ? i : (n - 1);

    unsigned idx = (unsigned)__builtin_nontemporal_load(indexes + ie);
    float px = __builtin_nontemporal_load(positions + 3 * ie + 0);
    float py = __builtin_nontemporal_load(positions + 3 * ie + 1);
    float pz = __builtin_nontemporal_load(positions + 3 * ie + 2);
    float a0 = base_sh[3 * idx + 0];
    float a1 = base_sh[3 * idx + 1];
    float a2 = base_sh[3 * idx + 2];

    unsigned fo = 45u * idx;
    const float4* W = (const float4*)(higher_sh + (fo & ~3u));
    float4 v[12];
    #pragma unroll
    for (int qq = 0; qq < 12; ++qq) v[qq] = W[qq];

    if (t < 64) {
        float h = 0.f;
        if (t < 32) {
            h = b1[t];
            #pragma unroll
            for (int k = 0; k < 16; ++k) h += glo[k] * w1[k * 32 + t];
        }
        float s = h;
        #pragma unroll
        for (int off = 32; off > 0; off >>= 1) s += __shfl_down(s, off);
        float mu = __shfl(s, 0) * (1.f / 32.f);
        float d = (t < 32) ? (h - mu) : 0.f;
        float v2 = d * d;
        #pragma unroll
        for (int off = 32; off > 0; off >>= 1) v2 += __shfl_down(v2, off);
        float var = __shfl(v2, 0) * (1.f / 32.f);
        float inv = rsqrtf(var + 1e-5f);
        if (t < 32) {
            float hv = (h - mu) * inv * ln_w[t] + ln_b[t];
            hsh[t] = hv > 0.f ? hv : 0.f;
        }
    }
    __syncthreads();
    if (t < 12) {
        float s2 = b2[t];
        #pragma unroll
        for (int jj = 0; jj < 32; ++jj) s2 += hsh[jj] * w2[jj * 12 + t];
        s2 *= 1e-12f;
        ssh[t] = fabsf(s2);
        float e = ((t & 3) == (t >> 2)) ? 1.f : 0.f;
        aff[t] = s2 + e;
    }
    __syncthreads();
    if (blockIdx.x == 0 && t == 0) {
        float sa = 0.f;
        #pragma unroll
        for (int q2 = 0; q2 < 12; ++q2) sa += ssh[q2];
        *mean_out = sa * (1.f / 12.f);
    }

    float dx = px - cam_pos[0];
    float dy = py - cam_pos[1];
    float dz = pz - cam_pos[2];
    float rn = rsqrtf(dx * dx + dy * dy + dz * dz);
    float x = dx * rn, y = dy * rn, z = dz * rn;
    float xx = x * x, yy = y * y, zz = z * z;
    float xy = x * y, yz = y * z, xz = x * z;

    float b[16];
    b[1]  = -0.4886025119029199f * y;
    b[2]  =  0.4886025119029199f * z;
    b[3]  = -0.4886025119029199f * x;
    b[4]  =  1.0925484305920792f * xy;
    b[5]  = -1.0925484305920792f * yz;
    b[6]  =  0.31539156525252005f * (2.f * zz - xx - yy);
    b[7]  = -1.0925484305920792f * xz;
    b[8]  =  0.5462742152960396f * (xx - yy);
    b[9]  = -0.5900435899266435f * y * (3.f * xx - yy);
    b[10] =  2.890611442640554f  * xy * z;
    b[11] = -0.4570457994644658f * y * (4.f * zz - xx - yy);
    b[12] =  0.3731763325901154f * z * (2.f * zz - 3.f * xx - 3.f * yy);
    b[13] = -0.4570457994644658f * x * (4.f * zz - xx - yy);
    b[14] =  1.445305721320277f  * z * (xx - yy);
    b[15] = -0.5900435899266435f * x * (xx - yy);

    const float C0 = 0.28209479177387814f;
    float c0 = a0 * C0 + 0.5f;
    float c1 = a1 * C0 + 0.5f;
    float c2 = a2 * C0 + 0.5f;

    float Wf[48];
    #pragma unroll
    for (int qq = 0; qq < 12; ++qq) {
        Wf[4 * qq + 0] = v[qq].x; Wf[4 * qq + 1] = v[qq].y;
        Wf[4 * qq + 2] = v[qq].z; Wf[4 * qq + 3] = v[qq].w;
    }

#define ACC(M)                                      \
    {                                               \
        _Pragma("unroll")                           \
        for (int k = 0; k < 15; ++k) {              \
            c0 += Wf[(M) + k]      * b[k + 1];      \
            c1 += Wf[(M) + 15 + k] * b[k + 1];      \
            c2 += Wf[(M) + 30 + k] * b[k + 1];      \
        }                                           \
    }
    switch (fo & 3u) {
        case 0: ACC(0) break;
        case 1: ACC(1) break;
        case 2: ACC(2) break;
        default: ACC(3) break;
    }
#undef ACC

    if (active) {
        #pragma unroll
        for (int rr = 0; rr < 3; ++rr) {
            float vv = c0 * aff[4 * rr + 0] + c1 * aff[4 * rr + 1] +
                       c2 * aff[4 * rr + 2] + aff[4 * rr + 3];
            vv = fminf(fmaxf(vv, 0.f), 1.f);
            __builtin_nontemporal_store(vv, out + 3 * i + rr);
        }
    }
}

extern "C" void kernel_launch(void* const* d_in, const int* in_sizes, int n_in,
                              void* d_out, int out_size, void* d_ws, size_t ws_size,
                              hipStream_t stream) {
    const float* positions = (const float*)d_in[0];
    const int*   indexes   = (const int*)d_in[1];
    const float* cam_pos   = (const float*)d_in[2];
    const float* glo       = (const float*)d_in[3];
    const float* base_sh   = (const float*)d_in[4];
    const float* higher_sh = (const float*)d_in[5];
    const float* w1        = (const float*)d_in[6];
    const float* b1        = (const float*)d_in[7];
    const float* ln_w      = (const float*)d_in[8];
    const float* ln_b      = (const float*)d_in[9];
    const float* w2        = (const float*)d_in[10];
    const float* b2        = (const float*)d_in[11];

    float* out = (float*)d_out;
    int n = in_sizes[0] / 3;                 // number of points
    int P = in_sizes[4] / 3;                 // NUM_POINTS (base_sh rows)
    float* mean_out = out + (out_size - 1);

    size_t need = (size_t)(2 * NB + n) * sizeof(int);
    int block = 256;
    int grid = (n + block - 1) / block;

    if (ws_size >= need && P > 0) {
        unsigned* hist    = (unsigned*)d_ws;          // [0,256)
        unsigned* cursors = hist + NB;                // [256,512)
        int*      perm    = (int*)(hist + 2 * NB);    // [512, 512+n)
        float scale = (float)NB / (float)P;

        zero_kernel<<<1, 512, 0, stream>>>(hist);
        hist_kernel<<<2048, 256, 0, stream>>>(indexes, hist, scale, n);
        scan_kernel<<<1, 64, 0, stream>>>(hist, cursors);
        int sgrid = (n + 256 * SC_ELEMS - 1) / (256 * SC_ELEMS);
        scatter_kernel<<<sgrid, 256, 0, stream>>>(indexes, cursors, perm,
                                                  scale, n);
        transfer_sh_perm<<<grid, block, 0, stream>>>(
            positions, indexes, perm, cam_pos, glo, base_sh, higher_sh,
            w1, b1, ln_w, ln_b, w2, b2, out, mean_out, n);
    } else {
        transfer_sh_fused<<<grid, block, 0, stream>>>(
            positions, indexes, cam_pos, glo, base_sh, higher_sh,
            w1, b1, ln_w, ln_b, w2, b2, out, mean_out, n);
    }
}

// Round 3
// 568.970 us; speedup vs baseline: 1.2127x; 1.2127x over previous
//
#include <hip/hip_runtime.h>
#include <math.h>

// ---------------------------------------------------------------------------
// TransferSH fused: per-point deg-3 SH evaluation + per-block recomputed
// per-frame affine MLP (tiny: 16->32->12, weights L2-resident).
// Single kernel. Streaming arrays (positions/indexes/out) use non-temporal
// loads/stores to preserve L2/L3 capacity for the 360MB higher_sh gather
// working set.
//
// R2 note: index-locality binning (256-bin counting sort + perm-ordered main
// kernel) was tried and REGRESSED: FETCH dropped 700->420MB as predicted, but
// effective BW fell 6.3->2.2 TB/s (divergent L3-hit gathers + random pos/out
// + perm dependent chain), main kernel 135->228us. Reverted to this version,
// which runs the compulsory ~720MB at ~90% of the random-gather HBM ceiling.
// ---------------------------------------------------------------------------

__global__ __launch_bounds__(256) void transfer_sh_fused(
    const float* __restrict__ positions,
    const int*   __restrict__ indexes,
    const float* __restrict__ cam_pos,
    const float* __restrict__ glo,
    const float* __restrict__ base_sh,
    const float* __restrict__ higher_sh,
    const float* __restrict__ w1,
    const float* __restrict__ b1,
    const float* __restrict__ ln_w,
    const float* __restrict__ ln_b,
    const float* __restrict__ w2,
    const float* __restrict__ b2,
    float* __restrict__ out,            // (N,3)
    float* __restrict__ mean_out,       // scalar tail of out buffer
    int n)
{
    __shared__ float aff[12];
    __shared__ float hsh[32];
    __shared__ float ssh[12];

    const int t = threadIdx.x;
    const int i = blockIdx.x * 256 + t;
    const bool active = (i < n);
    const int ie = active ? i : (n - 1);   // clamp so tail threads stay
                                           // barrier-safe (no early return)

    // ---- issue ALL per-point loads first: gather latency (~900cy) overlaps
    //      the per-block MLP prologue below ----
    unsigned idx = (unsigned)__builtin_nontemporal_load(indexes + ie);

    float px = __builtin_nontemporal_load(positions + 3 * ie + 0);
    float py = __builtin_nontemporal_load(positions + 3 * ie + 1);
    float pz = __builtin_nontemporal_load(positions + 3 * ie + 2);

    // base_sh gather: 3 scalar loads (12B random -> one line; 24MB L3-resident)
    float a0 = base_sh[3 * idx + 0];
    float a1 = base_sh[3 * idx + 1];
    float a2 = base_sh[3 * idx + 2];

    // higher_sh gather: 45 floats at float-offset fo = 45*idx (4B-aligned
    // only). Read the enclosing 16B-aligned 192B window as 12 float4
    // (misalign m = fo&3 <= 3, m+45 <= 48 always covers the row).
    unsigned fo = 45u * idx;
    const float4* W = (const float4*)(higher_sh + (fo & ~3u));
    float4 v[12];
    #pragma unroll
    for (int q = 0; q < 12; ++q) v[q] = W[q];

    // ---- per-block affine MLP on wave 0 (redundant per block; weights are
    //      L2-resident, ~900 FLOPs). Lanes 0-31 own hidden units; 64-wide
    //      shuffle reduce for LayerNorm stats (lanes >=32 contribute 0). ----
    if (t < 64) {
        float h = 0.f;
        if (t < 32) {
            h = b1[t];
            #pragma unroll
            for (int k = 0; k < 16; ++k) h += glo[k] * w1[k * 32 + t];
        }
        float s = h;
        #pragma unroll
        for (int off = 32; off > 0; off >>= 1) s += __shfl_down(s, off);
        float mu = __shfl(s, 0) * (1.f / 32.f);
        float d = (t < 32) ? (h - mu) : 0.f;
        float v2 = d * d;
        #pragma unroll
        for (int off = 32; off > 0; off >>= 1) v2 += __shfl_down(v2, off);
        float var = __shfl(v2, 0) * (1.f / 32.f);
        float inv = rsqrtf(var + 1e-5f);
        if (t < 32) {
            float hv = (h - mu) * inv * ln_w[t] + ln_b[t];
            hsh[t] = hv > 0.f ? hv : 0.f;
        }
    }
    __syncthreads();
    if (t < 12) {
        float s2 = b2[t];
        #pragma unroll
        for (int j = 0; j < 32; ++j) s2 += hsh[j] * w2[j * 12 + t];
        s2 *= 1e-12f;                                 // affine_res element
        ssh[t] = fabsf(s2);
        float e = ((t & 3) == (t >> 2)) ? 1.f : 0.f;  // eye(3,4) diag 0,5,10
        aff[t] = s2 + e;
    }
    __syncthreads();
    if (blockIdx.x == 0 && t == 0) {
        float sa = 0.f;
        #pragma unroll
        for (int q2 = 0; q2 < 12; ++q2) sa += ssh[q2];
        *mean_out = sa * (1.f / 12.f);
    }

    // ---- per-point compute (loads above are completing under this) ----
    float dx = px - cam_pos[0];
    float dy = py - cam_pos[1];
    float dz = pz - cam_pos[2];
    float rn = rsqrtf(dx * dx + dy * dy + dz * dz);
    float x = dx * rn, y = dy * rn, z = dz * rn;

    float xx = x * x, yy = y * y, zz = z * z;
    float xy = x * y, yz = y * z, xz = x * z;

    // deg-3 SH basis (b[0] folded into base term below)
    float b[16];
    b[1]  = -0.4886025119029199f * y;
    b[2]  =  0.4886025119029199f * z;
    b[3]  = -0.4886025119029199f * x;
    b[4]  =  1.0925484305920792f * xy;
    b[5]  = -1.0925484305920792f * yz;
    b[6]  =  0.31539156525252005f * (2.f * zz - xx - yy);
    b[7]  = -1.0925484305920792f * xz;
    b[8]  =  0.5462742152960396f * (xx - yy);
    b[9]  = -0.5900435899266435f * y * (3.f * xx - yy);
    b[10] =  2.890611442640554f  * xy * z;
    b[11] = -0.4570457994644658f * y * (4.f * zz - xx - yy);
    b[12] =  0.3731763325901154f * z * (2.f * zz - 3.f * xx - 3.f * yy);
    b[13] = -0.4570457994644658f * x * (4.f * zz - xx - yy);
    b[14] =  1.445305721320277f  * z * (xx - yy);
    b[15] = -0.5900435899266435f * x * (xx - yy);

    const float C0 = 0.28209479177387814f;
    float c0 = a0 * C0 + 0.5f;
    float c1 = a1 * C0 + 0.5f;
    float c2 = a2 * C0 + 0.5f;

    float Wf[48];
    #pragma unroll
    for (int q = 0; q < 12; ++q) {
        Wf[4 * q + 0] = v[q].x; Wf[4 * q + 1] = v[q].y;
        Wf[4 * q + 2] = v[q].z; Wf[4 * q + 3] = v[q].w;
    }

#define ACC(M)                                      \
    {                                               \
        _Pragma("unroll")                           \
        for (int k = 0; k < 15; ++k) {              \
            c0 += Wf[(M) + k]      * b[k + 1];      \
            c1 += Wf[(M) + 15 + k] * b[k + 1];      \
            c2 += Wf[(M) + 30 + k] * b[k + 1];      \
        }                                           \
    }
    switch (fo & 3u) {
        case 0: ACC(0) break;
        case 1: ACC(1) break;
        case 2: ACC(2) break;
        default: ACC(3) break;
    }
#undef ACC

    // affine from LDS (broadcast) + clamp + nt store
    if (active) {
        #pragma unroll
        for (int r = 0; r < 3; ++r) {
            float vv = c0 * aff[4 * r + 0] + c1 * aff[4 * r + 1] +
                       c2 * aff[4 * r + 2] + aff[4 * r + 3];
            vv = fminf(fmaxf(vv, 0.f), 1.f);
            __builtin_nontemporal_store(vv, out + 3 * i + r);
        }
    }
}

extern "C" void kernel_launch(void* const* d_in, const int* in_sizes, int n_in,
                              void* d_out, int out_size, void* d_ws, size_t ws_size,
                              hipStream_t stream) {
    const float* positions = (const float*)d_in[0];
    const int*   indexes   = (const int*)d_in[1];
    const float* cam_pos   = (const float*)d_in[2];
    const float* glo       = (const float*)d_in[3];
    const float* base_sh   = (const float*)d_in[4];
    const float* higher_sh = (const float*)d_in[5];
    const float* w1        = (const float*)d_in[6];
    const float* b1        = (const float*)d_in[7];
    const float* ln_w      = (const float*)d_in[8];
    const float* ln_b      = (const float*)d_in[9];
    const float* w2        = (const float*)d_in[10];
    const float* b2        = (const float*)d_in[11];

    float* out = (float*)d_out;

    int n = in_sizes[0] / 3;                 // number of points
    float* mean_out = out + (out_size - 1);  // scalar output at tail

    int block = 256;
    int grid = (n + block - 1) / block;
    transfer_sh_fused<<<grid, block, 0, stream>>>(
        positions, indexes, cam_pos, glo, base_sh, higher_sh,
        w1, b1, ln_w, ln_b, w2, b2, out, mean_out, n);
}